// Round 1
// 3364.042 us; speedup vs baseline: 1.1899x; 1.1899x over previous
//
#include <hip/hip_runtime.h>
#include <stdint.h>
#include <stddef.h>

#define TT     4096   // B*S tokens
#define HIDN   4096
#define NHEAD  32
#define NKVH   8
#define HDIM   128
#define INTERN 14336
#define QKVN   6144   // (NH + 2*NKV) * HD
#define SEQL   1024

typedef unsigned short u16;
typedef __attribute__((ext_vector_type(4))) float f32x4;
typedef __attribute__((ext_vector_type(8))) short s16x8;
typedef __attribute__((ext_vector_type(4))) unsigned short u16x4;

__device__ __forceinline__ u16 f2bf(float f) {
  union { float f; unsigned u; } un; un.f = f;
  unsigned r = un.u + 0x7fffu + ((un.u >> 16) & 1u);
  return (u16)(r >> 16);
}
__device__ __forceinline__ float bf2f(u16 h) {
  union { unsigned u; float f; } un; un.u = ((unsigned)h) << 16;
  return un.f;
}
// async global->LDS, 16B per lane; lds ptr must be wave-uniform base (lane*16 auto)
__device__ __forceinline__ void gl_lds16(const void* g, void* l) {
  __builtin_amdgcn_global_load_lds((const __attribute__((address_space(1))) void*)g,
                                   (__attribute__((address_space(3))) void*)l, 16, 0, 0);
}

// ---------------- fused (optional add) + layernorm -> bf16 ----------------
__global__ __launch_bounds__(256) void add_ln_kernel(
    const float* __restrict__ x, const float* __restrict__ res,
    const float* __restrict__ w, const float* __restrict__ b,
    float* __restrict__ h_out, u16* __restrict__ normed)
{
  const int row = blockIdx.x;
  const int tid = threadIdx.x;
  const size_t base = (size_t)row * HIDN;
  float4 v[4];
  float sum = 0.f, sq = 0.f;
#pragma unroll
  for (int i = 0; i < 4; ++i) {
    const int idx = (tid + i * 256) * 4;
    float4 a = *(const float4*)(x + base + idx);
    if (res) {
      float4 r2 = *(const float4*)(res + base + idx);
      a.x += r2.x; a.y += r2.y; a.z += r2.z; a.w += r2.w;
    }
    v[i] = a;
    sum += a.x + a.y + a.z + a.w;
    sq  += a.x * a.x + a.y * a.y + a.z * a.z + a.w * a.w;
  }
  __shared__ float red[8];
  const int lane = tid & 63, wv = tid >> 6;
#pragma unroll
  for (int off = 32; off >= 1; off >>= 1) {
    sum += __shfl_down(sum, off);
    sq  += __shfl_down(sq, off);
  }
  if (lane == 0) { red[wv] = sum; red[4 + wv] = sq; }
  __syncthreads();
  sum = red[0] + red[1] + red[2] + red[3];
  sq  = red[4] + red[5] + red[6] + red[7];
  const float mean = sum * (1.f / HIDN);
  const float var  = sq * (1.f / HIDN) - mean * mean;
  const float rstd = rsqrtf(var + 1e-5f);
#pragma unroll
  for (int i = 0; i < 4; ++i) {
    const int idx = (tid + i * 256) * 4;
    if (h_out) *(float4*)(h_out + base + idx) = v[i];
    float4 wv4 = *(const float4*)(w + idx);
    float4 bv4 = *(const float4*)(b + idx);
    u16x4 o;
    o.x = f2bf((v[i].x - mean) * rstd * wv4.x + bv4.x);
    o.y = f2bf((v[i].y - mean) * rstd * wv4.y + bv4.y);
    o.z = f2bf((v[i].z - mean) * rstd * wv4.z + bv4.z);
    o.w = f2bf((v[i].w - mean) * rstd * wv4.w + bv4.w);
    *(u16x4*)(normed + base + idx) = o;
  }
}

// ---------- fp32 (K x N) -> bf16 transposed (N x K) ----------
__global__ __launch_bounds__(256) void convtrans_kernel(
    const float* __restrict__ W, u16* __restrict__ Wt, const int K, const int N)
{
  __shared__ float tile[64 * 65];
  const int k0 = blockIdx.x * 64;
  const int n0 = blockIdx.y * 64;
  const int tid = threadIdx.x;
  const int c4 = (tid & 15) * 4;
  const int r  = tid >> 4;
#pragma unroll
  for (int p = 0; p < 4; ++p) {
    const int rr = r + p * 16;
    float4 v4 = *(const float4*)(W + (size_t)(k0 + rr) * N + n0 + c4);
    tile[rr * 65 + c4 + 0] = v4.x;
    tile[rr * 65 + c4 + 1] = v4.y;
    tile[rr * 65 + c4 + 2] = v4.z;
    tile[rr * 65 + c4 + 3] = v4.w;
  }
  __syncthreads();
#pragma unroll
  for (int p = 0; p < 4; ++p) {
    const int nl = r + p * 16;
    u16x4 o;
    o.x = f2bf(tile[(c4 + 0) * 65 + nl]);
    o.y = f2bf(tile[(c4 + 1) * 65 + nl]);
    o.z = f2bf(tile[(c4 + 2) * 65 + nl]);
    o.w = f2bf(tile[(c4 + 3) * 65 + nl]);
    *(u16x4*)(Wt + (size_t)(n0 + nl) * K + k0 + c4) = o;
  }
}

// ---------- bf16 GEMM  C(M x N) = A(M x K) * Bt(N x K)^T ----------
// 256x256 tile, BK=64, 8 waves (2Mx4N), 8-phase schedule with counted vmcnt
// (T2 XOR-swizzle + T3/T4 counted-vmcnt phases + T5 setprio).
// MODE 0: C_bf16 = acc + bias          (qkv)
// MODE 1: C_f32  = acc + addsrc        (o-proj + residual)
// MODE 2: C_f32  = acc + bias          (down)
// MODE 3: C_bf16 = gegelu(acc + bias)  (up; ldc = N/2)
template <int MODE>
__global__ __launch_bounds__(512, 2) void gemm256_kernel(
    const u16* __restrict__ A, const u16* __restrict__ Bt,
    const float* __restrict__ bias, const float* __restrict__ addsrc,
    void* __restrict__ Cout, const int N, const int K, const int ldc)
{
  // 2 x (A 256x64 + B 256x64) bf16 = 128 KiB exactly
  __shared__ u16 As[2][256 * 64];
  __shared__ u16 Bs[2][256 * 64];

  const int NT = K >> 6;                // K tiles of 64
  const int grid_n = N >> 8;            // N / 256
  const int nwg = (int)gridDim.x;       // divisible by 8 for all our shapes
  const int cpx = nwg >> 3;
  const int pid = (int)blockIdx.x;
  const int vid = (pid & 7) * cpx + (pid >> 3);  // XCD-contiguous chunks
  const int bm = vid / grid_n;
  const int bn = vid % grid_n;

  const int tid  = threadIdx.x;
  const int lane = tid & 63;
  const int wv   = tid >> 6;            // 0..7
  const int wm   = wv >> 2;             // 0..1  (M half)
  const int wn   = wv & 3;              // 0..3  (N quarter)
  const int quad = lane >> 4, l16 = lane & 15;

  // ---- staging addresses: linear LDS dest, inverse-swizzled global source ----
  // LDS rows are 128B (64 bf16) = 8 granules of 16B; swizzle: granule ^= row&7.
  const int stRow = tid >> 3;                         // 0..63 within one 64-row load
  const int csrc  = ((tid & 7) ^ (stRow & 7)) * 8;    // pre-swizzled source col (elems)
  const u16* Abase = A  + ((size_t)bm * 256 + stRow) * K + csrc;
  const u16* Bbase = Bt + ((size_t)bn * 256 + stRow) * K + csrc;

  // stage one 64-row load L of operand A/B for K-tile kt (2 gl_lds per phase total).
  // For kt >= NT: clamp SOURCE to tile 0 (valid memory), keep normal dest so the
  // per-wave vmcnt ledger stays exact; garbage lands in slots never computed.
  auto stg = [&](int kt, bool isA, int L) {
    const int kts = (kt < NT) ? kt : 0;
    const u16* g = (isA ? Abase : Bbase) + (size_t)L * 64 * K + (size_t)kts * 64;
    u16* d = (isA ? As[kt & 1] : Bs[kt & 1]) + (L * 64 + wv * 8) * 64;
    gl_lds16(g, d);
  };

  // ---- fragment read offsets (bytes), swizzled to match staging ----
  const int cswz0 = (((0 * 4 + quad)) ^ (l16 & 7)) * 16;   // kk=0
  const int cswz1 = (((1 * 4 + quad)) ^ (l16 & 7)) * 16;   // kk=1
  const int arow  = (wm * 128 + l16) * 128;
  const int brow  = (wn * 64 + l16) * 128;

  // ---- prologue: tile0 fully (8 loads), then 6 of tile1; retire tile0, keep 6 in flight
  stg(0, false, 0); stg(0, false, 1); stg(0, false, 2); stg(0, false, 3);
  stg(0, true, 0);  stg(0, true, 2);  stg(0, true, 1);  stg(0, true, 3);
  stg(1, false, 0); stg(1, false, 1); stg(1, false, 2); stg(1, false, 3);
  stg(1, true, 0);  stg(1, true, 2);
  asm volatile("s_waitcnt vmcnt(6)" ::: "memory");
  __builtin_amdgcn_s_barrier();
  asm volatile("" ::: "memory");

  f32x4 acc[8][4] = {};

  for (int t = 0; t < NT; ++t) {
    const int cur = t & 1;
    const char* Ab = (const char*)As[cur];
    const char* Bb = (const char*)Bs[cur];
    s16x8 bfr[4][2];
#pragma unroll
    for (int p = 0; p < 4; ++p) {
      // -- ds-load register subtile (A: 2 M-frags x 2 k-halves; +B all in phase 0)
      s16x8 af[2][2];
#pragma unroll
      for (int i = 0; i < 2; ++i) {
        af[i][0] = *(const s16x8*)(Ab + arow + (p * 2 + i) * 2048 + cswz0);
        af[i][1] = *(const s16x8*)(Ab + arow + (p * 2 + i) * 2048 + cswz1);
      }
      if (p == 0) {
#pragma unroll
        for (int j = 0; j < 4; ++j) {
          bfr[j][0] = *(const s16x8*)(Bb + brow + j * 2048 + cswz0);
          bfr[j][1] = *(const s16x8*)(Bb + brow + j * 2048 + cswz1);
        }
        // (t+1).A hi-halves: those rows' last readers were phases 2,3 of tile t-1
        stg(t + 1, true, 1); stg(t + 1, true, 3);
      } else if (p == 1) {
        // B of tile t+2: B[cur] fully consumed in phase 0
        stg(t + 2, false, 0); stg(t + 2, false, 1);
      } else if (p == 2) {
        stg(t + 2, false, 2); stg(t + 2, false, 3);
      } else {
        // (t+2).A lo-halves: rows consumed in phases 0,1
        stg(t + 2, true, 0); stg(t + 2, true, 2);
        // once per K-tile: retire exactly tile t+1's 8 loads, keep 6 in flight
        asm volatile("s_waitcnt vmcnt(6)" ::: "memory");
      }
      asm volatile("" ::: "memory");
      __builtin_amdgcn_s_barrier();
      asm volatile("" ::: "memory");
      __builtin_amdgcn_s_setprio(1);
#pragma unroll
      for (int i = 0; i < 2; ++i)
#pragma unroll
        for (int j = 0; j < 4; ++j) {
          acc[p * 2 + i][j] = __builtin_amdgcn_mfma_f32_16x16x32_bf16(
              af[i][0], bfr[j][0], acc[p * 2 + i][j], 0, 0, 0);
          acc[p * 2 + i][j] = __builtin_amdgcn_mfma_f32_16x16x32_bf16(
              af[i][1], bfr[j][1], acc[p * 2 + i][j], 0, 0, 0);
        }
      __builtin_amdgcn_s_setprio(0);
      asm volatile("" ::: "memory");
      __builtin_amdgcn_s_barrier();
      asm volatile("" ::: "memory");
    }
  }
  asm volatile("s_waitcnt vmcnt(0)" ::: "memory");

  // ---- epilogue ----
#pragma unroll
  for (int i = 0; i < 8; ++i) {
    const int row0 = bm * 256 + wm * 128 + i * 16 + quad * 4;
#pragma unroll
    for (int j = 0; j < 4; ++j) {
      const int col = bn * 256 + wn * 64 + j * 16 + l16;
#pragma unroll
      for (int rr = 0; rr < 4; ++rr) {
        float vv = acc[i][j][rr];
        if (MODE == 0) {
          ((u16*)Cout)[(size_t)(row0 + rr) * ldc + col] = f2bf(vv + bias[col]);
        } else if (MODE == 1) {
          const size_t off = (size_t)(row0 + rr) * ldc + col;
          ((float*)Cout)[off] = vv + addsrc[off];
        } else if (MODE == 2) {
          ((float*)Cout)[(size_t)(row0 + rr) * ldc + col] = vv + bias[col];
        } else {
          vv += bias[col];
          float other = __shfl_xor(vv, 1);
          if ((l16 & 1) == 0) {
            float aa  = fminf(vv, 20.f);
            float lin = fminf(fmaxf(other, -20.f), 20.f);
            float g = aa / (1.f + __expf(-1.702f * aa)) * (lin + 1.f);
            ((u16*)Cout)[(size_t)(row0 + rr) * ldc + (col >> 1)] = f2bf(g);
          }
        }
      }
    }
  }
}

// ---------- RoPE in place on q,k inside qkv buffer ----------
__global__ __launch_bounds__(256) void rope_kernel(
    u16* __restrict__ qkv, const float* __restrict__ cosb, const float* __restrict__ sinb)
{
  const int idx  = blockIdx.x * 256 + threadIdx.x; // TT * 40 * 64
  const int d    = idx & 63;
  const int rest = idx >> 6;
  const int hh   = rest % 40;
  const int t    = rest / 40;
  const int col  = (hh < 32) ? hh * 128 : 4096 + (hh - 32) * 128;
  const size_t base = (size_t)t * QKVN + col;
  const float x1 = bf2f(qkv[base + d]);
  const float x2 = bf2f(qkv[base + d + 64]);
  const float c = cosb[t * 64 + d];
  const float s = sinb[t * 64 + d];
  qkv[base + d]      = f2bf(x1 * c - x2 * s);
  qkv[base + d + 64] = f2bf(x2 * c + x1 * s);
}

// ---------- causal GQA flash attention ----------
// block: one (batch, head, 64-row q tile); 4 waves x 16 q rows; 64-key tiles
__global__ __launch_bounds__(256) void flash_kernel(
    const u16* __restrict__ qkv, u16* __restrict__ ctx)
{
  __shared__ u16 Qs[64 * 128];
  __shared__ u16 Ks[64 * 128];
  __shared__ u16 Vt[128 * 72];   // transposed V tile, padded rows (72 elems = 144B)
  __shared__ u16 Ps[4 * 16 * 72];

  const int qt = (int)gridDim.x - 1 - (int)blockIdx.x; // big tiles first
  const int h  = blockIdx.y;
  const int bz = blockIdx.z;
  const int kvh = h >> 2;

  const int tid = threadIdx.x, lane = tid & 63, wv = tid >> 6;
  const int quad = lane >> 4, l16 = lane & 15;

  const size_t tok0 = (size_t)bz * SEQL + (size_t)qt * 64;
  const u16* qg  = qkv + tok0 * QKVN + h * HDIM;
  const u16* kg0 = qkv + (size_t)bz * SEQL * QKVN + 4096 + kvh * HDIM;
  const u16* vg0 = qkv + (size_t)bz * SEQL * QKVN + 5120 + kvh * HDIM;

  const int qrow = tid >> 4;
  const int qcol = (tid & 15) * 8;
#pragma unroll
  for (int j = 0; j < 4; ++j)
    gl_lds16(qg + (size_t)(j * 16 + qrow) * QKVN + qcol, Qs + j * 2048 + wv * 512);

  f32x4 oacc[8] = {};
  float m_i[4], l_i[4];
#pragma unroll
  for (int r = 0; r < 4; ++r) { m_i[r] = -INFINITY; l_i[r] = 0.f; }

  const int vhd = tid & 127;
  const int vkq = tid >> 7;

  for (int kt = 0; kt <= qt; ++kt) {
    __syncthreads();
    const u16* kg = kg0 + (size_t)(kt * 64) * QKVN;
    const u16* vg = vg0 + (size_t)(kt * 64) * QKVN;
#pragma unroll
    for (int j = 0; j < 4; ++j)
      gl_lds16(kg + (size_t)(j * 16 + qrow) * QKVN + qcol, Ks + j * 2048 + wv * 512);
#pragma unroll
    for (int j = 0; j < 8; ++j) {
      const int kk0 = (j * 2 + vkq) * 4;
      u16x4 pk;
      pk.x = vg[(size_t)(kk0 + 0) * QKVN + vhd];
      pk.y = vg[(size_t)(kk0 + 1) * QKVN + vhd];
      pk.z = vg[(size_t)(kk0 + 2) * QKVN + vhd];
      pk.w = vg[(size_t)(kk0 + 3) * QKVN + vhd];
      *(u16x4*)(Vt + vhd * 72 + kk0) = pk;
    }
    __syncthreads();

    // S = Q K^T for this wave's 16 q rows x 64 keys
    f32x4 sacc[4] = {};
#pragma unroll
    for (int ks = 0; ks < 4; ++ks) {
      s16x8 aq = *(const s16x8*)(Qs + (wv * 16 + l16) * 128 + ks * 32 + quad * 8);
#pragma unroll
      for (int jt = 0; jt < 4; ++jt) {
        s16x8 bk = *(const s16x8*)(Ks + (jt * 16 + l16) * 128 + ks * 32 + quad * 8);
        sacc[jt] = __builtin_amdgcn_mfma_f32_16x16x32_bf16(aq, bk, sacc[jt], 0, 0, 0);
      }
    }

    const bool diag = (kt == qt);
    const int qrb = wv * 16 + quad * 4;
#pragma unroll
    for (int jt = 0; jt < 4; ++jt)
#pragma unroll
      for (int r = 0; r < 4; ++r) {
        float sv = sacc[jt][r] * 0.08838834764831845f;
        if (diag && (jt * 16 + l16) > (qrb + r)) sv = -INFINITY;
        sacc[jt][r] = sv;
      }

    float alpha[4];
#pragma unroll
    for (int r = 0; r < 4; ++r) {
      float mx = fmaxf(fmaxf(sacc[0][r], sacc[1][r]), fmaxf(sacc[2][r], sacc[3][r]));
      mx = fmaxf(mx, __shfl_xor(mx, 1));
      mx = fmaxf(mx, __shfl_xor(mx, 2));
      mx = fmaxf(mx, __shfl_xor(mx, 4));
      mx = fmaxf(mx, __shfl_xor(mx, 8));
      const float mn = fmaxf(m_i[r], mx);
      alpha[r] = __expf(m_i[r] - mn);
      m_i[r] = mn;
    }
#pragma unroll
    for (int jt = 0; jt < 4; ++jt)
#pragma unroll
      for (int r = 0; r < 4; ++r)
        sacc[jt][r] = __expf(sacc[jt][r] - m_i[r]);
#pragma unroll
    for (int r = 0; r < 4; ++r) {
      float sm = sacc[0][r] + sacc[1][r] + sacc[2][r] + sacc[3][r];
      sm += __shfl_xor(sm, 1);
      sm += __shfl_xor(sm, 2);
      sm += __shfl_xor(sm, 4);
      sm += __shfl_xor(sm, 8);
      l_i[r] = l_i[r] * alpha[r] + sm;
    }
#pragma unroll
    for (int t8 = 0; t8 < 8; ++t8)
#pragma unroll
      for (int r = 0; r < 4; ++r)
        oacc[t8][r] *= alpha[r];

    // P (C layout) -> wave-private LDS -> A layout
    u16* Pw = Ps + wv * 1152;
#pragma unroll
    for (int jt = 0; jt < 4; ++jt)
#pragma unroll
      for (int r = 0; r < 4; ++r)
        Pw[(quad * 4 + r) * 72 + jt * 16 + l16] = f2bf(sacc[jt][r]);

#pragma unroll
    for (int ks2 = 0; ks2 < 2; ++ks2) {
      s16x8 ap = *(const s16x8*)(Pw + l16 * 72 + ks2 * 32 + quad * 8);
#pragma unroll
      for (int t8 = 0; t8 < 8; ++t8) {
        s16x8 bv = *(const s16x8*)(Vt + (t8 * 16 + l16) * 72 + ks2 * 32 + quad * 8);
        oacc[t8] = __builtin_amdgcn_mfma_f32_16x16x32_bf16(ap, bv, oacc[t8], 0, 0, 0);
      }
    }
  }

  float inv[4];
#pragma unroll
  for (int r = 0; r < 4; ++r) inv[r] = 1.f / l_i[r];
#pragma unroll
  for (int t8 = 0; t8 < 8; ++t8)
#pragma unroll
    for (int r = 0; r < 4; ++r) {
      const size_t row = tok0 + wv * 16 + quad * 4 + r;
      ctx[row * (size_t)HIDN + h * HDIM + t8 * 16 + l16] = f2bf(oacc[t8][r] * inv[r]);
    }
}

extern "C" void kernel_launch(void* const* d_in, const int* in_sizes, int n_in,
                              void* d_out, int out_size, void* d_ws, size_t ws_size,
                              hipStream_t stream) {
  (void)in_sizes; (void)n_in; (void)out_size; (void)ws_size;
  const float* hs    = (const float*)d_in[0];
  const float* resid = (const float*)d_in[1];
  const float* cosb  = (const float*)d_in[2];
  const float* sinb  = (const float*)d_in[3];
  const float* w_qkv = (const float*)d_in[5];
  const float* b_qkv = (const float*)d_in[6];
  const float* w_o   = (const float*)d_in[7];
  const float* w_ln1 = (const float*)d_in[8];
  const float* b_ln1 = (const float*)d_in[9];
  const float* w_ln2 = (const float*)d_in[10];
  const float* b_ln2 = (const float*)d_in[11];
  const float* w_up  = (const float*)d_in[12];
  const float* b_up  = (const float*)d_in[13];
  const float* w_dn  = (const float*)d_in[14];
  const float* b_dn  = (const float*)d_in[15];

  float* mlp_out = (float*)d_out;
  float* h2      = mlp_out + (size_t)TT * HIDN;

  char* ws = (char*)d_ws;
  float* h_buf  = (float*)ws;                   // 67,108,864 B
  u16*   normed = (u16*)(ws + 67108864ULL);     // 33,554,432 B
  u16*   qkv    = (u16*)(ws + 100663296ULL);    // 50,331,648 B
  u16*   ctx    = (u16*)(ws + 150994944ULL);    // 33,554,432 B
  u16*   act    = (u16*)(ws + 100663296ULL);    // 117,440,512 B (aliases dead qkv/ctx)
  u16*   warena = (u16*)(ws + 218103808ULL);    // 234,881,024 B max (w_up^T)
  // total ws use: 452,984,832 B

  // 1: h = hs + res ; normed = LN1(h)
  add_ln_kernel<<<TT, 256, 0, stream>>>(hs, resid, w_ln1, b_ln1, h_buf, normed);
  // 2: w_qkv -> bf16 transposed
  convtrans_kernel<<<dim3(HIDN / 64, QKVN / 64), 256, 0, stream>>>(w_qkv, warena, HIDN, QKVN);
  // 3: qkv = normed @ w_qkv + b_qkv
  gemm256_kernel<0><<<(TT / 256) * (QKVN / 256), 512, 0, stream>>>(
      normed, warena, b_qkv, nullptr, qkv, QKVN, HIDN, QKVN);
  // 4: rope q,k in place
  rope_kernel<<<(TT * 40 * 64) / 256, 256, 0, stream>>>(qkv, cosb, sinb);
  // 5: flash attention -> ctx
  flash_kernel<<<dim3(SEQL / 64, NHEAD, 4), 256, 0, stream>>>(qkv, ctx);
  // 6: w_o -> bf16 transposed
  convtrans_kernel<<<dim3(HIDN / 64, HIDN / 64), 256, 0, stream>>>(w_o, warena, HIDN, HIDN);
  // 7: h2 = ctx @ w_o + h
  gemm256_kernel<1><<<(TT / 256) * (HIDN / 256), 512, 0, stream>>>(
      ctx, warena, nullptr, h_buf, h2, HIDN, HIDN, HIDN);
  // 8: normed = LN2(h2)
  add_ln_kernel<<<TT, 256, 0, stream>>>(h2, nullptr, w_ln2, b_ln2, nullptr, normed);
  // 9: w_up -> bf16 transposed
  convtrans_kernel<<<dim3(HIDN / 64, (2 * INTERN) / 64), 256, 0, stream>>>(w_up, warena, HIDN, 2 * INTERN);
  // 10: act = gegelu(normed @ w_up + b_up)
  gemm256_kernel<3><<<(TT / 256) * ((2 * INTERN) / 256), 512, 0, stream>>>(
      normed, warena, b_up, nullptr, act, 2 * INTERN, HIDN, INTERN);
  // 11: w_down -> bf16 transposed
  convtrans_kernel<<<dim3(INTERN / 64, HIDN / 64), 256, 0, stream>>>(w_dn, warena, INTERN, HIDN);
  // 12: mlp_out = act @ w_down + b_down
  gemm256_kernel<2><<<(TT / 256) * (HIDN / 256), 512, 0, stream>>>(
      act, warena, b_dn, nullptr, mlp_out, HIDN, INTERN, HIDN);
}